// Round 6
// baseline (114.445 us; speedup 1.0000x reference)
//
#include <hip/hip_runtime.h>

// Problem sizes (fixed by the reference)
#define BDIM 8
#define QDIM 1024
#define KDIM 1024
#define HDIM 64   // = DQ = DK = DV
#define KTPC 4    // k-tiles (64 keys each) per chunk  -> <=4 chunks per b
#define MAXCH 4

constexpr float kLog2e = 1.4426950408889634f;
constexpr float kC2 = 2.0f * kLog2e;

// tanh(x) = 1 - 2/(1 + e^{2x}); e^{2x} = Eq*Ek with Eq=2^{kC2*qhat},
// Ek=2^{kC2*khat} precomputed. Per element: fma, rcp, fma (3 VALU ops).
// Rails exact: Eq*Ek -> inf => rcp -> 0 => tanh -> 1.
__device__ __forceinline__ float sigp(float eq, float ek) {
  return __builtin_amdgcn_rcpf(fmaf(eq, ek, 1.0f));
}

// ---------------------------------------------------------------------------
// K1: both projections in one launch; emits Eq/Ek = exp2(kC2 * (X@W)).
// ---------------------------------------------------------------------------
__global__ __launch_bounds__(256) void proj_both(
    const float* __restrict__ queries, const float* __restrict__ keys,
    const float* __restrict__ Wq, const float* __restrict__ Wk,
    float* __restrict__ eq, float* __restrict__ ek) {
  const int bid = blockIdx.x;
  const bool isK = bid >= 128;
  const float* X = isK ? keys : queries;
  const float* W = isK ? Wk : Wq;
  float* Y = isK ? ek : eq;
  const long long base = (long long)(bid & 127) * 64 * 64;

  __shared__ __align__(16) float xs[64][68];
  __shared__ __align__(16) float ws[64][64];
  const int t = threadIdx.x;
  {
    const int r = t >> 4, sl = t & 15;
#pragma unroll
    for (int i = 0; i < 4; ++i) {
      *(float4*)&xs[r + i * 16][sl * 4] =
          *(const float4*)&X[base + (long long)(r + i * 16) * 64 + sl * 4];
      *(float4*)&ws[r + i * 16][sl * 4] =
          *(const float4*)&W[(r + i * 16) * 64 + sl * 4];
    }
  }
  __syncthreads();

  const int r = t >> 2;
  const int c0 = (t & 3) * 16;
  float acc[16];
#pragma unroll
  for (int j = 0; j < 16; ++j) acc[j] = 0.0f;

#pragma unroll 8
  for (int d = 0; d < 64; ++d) {
    const float xv = xs[r][d];
#pragma unroll
    for (int j4 = 0; j4 < 4; ++j4) {
      float4 w4 = *(float4*)&ws[d][c0 + j4 * 4];
      acc[j4 * 4 + 0] = fmaf(xv, w4.x, acc[j4 * 4 + 0]);
      acc[j4 * 4 + 1] = fmaf(xv, w4.y, acc[j4 * 4 + 1]);
      acc[j4 * 4 + 2] = fmaf(xv, w4.z, acc[j4 * 4 + 2]);
      acc[j4 * 4 + 3] = fmaf(xv, w4.w, acc[j4 * 4 + 3]);
    }
  }
#pragma unroll
  for (int j4 = 0; j4 < 4; ++j4) {
    float4 o = make_float4(__builtin_amdgcn_exp2f(acc[j4 * 4 + 0] * kC2),
                           __builtin_amdgcn_exp2f(acc[j4 * 4 + 1] * kC2),
                           __builtin_amdgcn_exp2f(acc[j4 * 4 + 2] * kC2),
                           __builtin_amdgcn_exp2f(acc[j4 * 4 + 3] * kC2));
    *(float4*)&Y[base + (long long)r * 64 + c0 + j4 * 4] = o;
  }
}

// ---------------------------------------------------------------------------
// K2: fused scores + online softmax + PV over one k-chunk (<=4 k-tiles).
// Block = (b, qtile32, chunk) from compacted worklist; 512 threads.
// Thread (tq=t>>4, kg=t&15): scores for 1q x 4k (round-3 proven pipeline),
// PV accumulator for (tq, d = kg*4..kg*4+3). Partial (m,l,o) -> workspace;
// scores NEVER touch HBM (this removes round-5's 87MB amplified write).
// ---------------------------------------------------------------------------
__global__ __launch_bounds__(512, 6) void fused_kernel(
    const float* __restrict__ eqp, const float* __restrict__ ekp,
    const float* __restrict__ vglob, const float* __restrict__ wv,
    const int* __restrict__ vlens, float* __restrict__ part_o,
    float2* __restrict__ part_ml) {
  // ---- uniform worklist mapping (scalar) ----
  int pre[9];
  pre[0] = 0;
#pragma unroll
  for (int bb = 0; bb < 8; ++bb) {
    int nt = (vlens[bb] + 63) >> 6;
    nt = nt < 16 ? nt : 16;
    const int nch = (nt + KTPC - 1) / KTPC;
    pre[bb + 1] = pre[bb] + (nch << 5);  // nch chunks x 32 q-tiles
  }
  const int g = blockIdx.x;
  if (g >= pre[8]) return;
  int b = 0;
#pragma unroll
  for (int i = 0; i < 7; ++i) b += (g >= pre[i + 1]);
  const int local = g - pre[b];
  const int q0 = (local & 31) * 32;  // q-tile fastest
  const int ch = local >> 5;
  const int vlen = vlens[b];
  int nt = (vlen + 63) >> 6;
  nt = nt < 16 ? nt : 16;
  const int kt0 = ch * KTPC;
  const int ktend = (kt0 + KTPC < nt) ? kt0 + KTPC : nt;

  __shared__ __align__(16) float qs[32][68];
  __shared__ __align__(16) float ks[64][64];  // XOR-swizzled Ek tile
  __shared__ __align__(16) float vs[64][64];  // V tile (linear)
  __shared__ __align__(16) float ps[32][68];  // attn-weight tile
  const int t = threadIdx.x;

  float sumw = 0.0f;
#pragma unroll
  for (int h = 0; h < 64; ++h) sumw += wv[h];  // uniform -> scalar loads

  {
    const int r = t >> 4, sl = t & 15;
    *(float4*)&qs[r][sl * 4] =
        *(const float4*)&eqp[(long long)(b * QDIM + q0 + r) * 64 + sl * 4];
  }

  const int tq = t >> 4;            // q row 0..31
  const int kg = t & 15;            // k group / d-slice group
  const int kbs = kg << 2;
  const int key0 = ((kbs + 0) ^ kg) & 15;
  const int key1 = ((kbs + 1) ^ kg) & 15;
  const int key2 = ((kbs + 2) ^ kg) & 15;
  const int key3 = ((kbs + 3) ^ kg) & 15;

  float4 o4 = make_float4(0, 0, 0, 0);
  float m = -3.0e38f, l = 0.0f;

  for (int kt = kt0; kt < ktend; ++kt) {
    __syncthreads();  // prev iteration done reading vs/ps
#pragma unroll
    for (int i = 0; i < 2; ++i) {
      const int f = i * 512 + t;
      const int k = f >> 4, sl = f & 15;
      const int key = (k ^ (k >> 2)) & 15;
      *(float4*)&ks[k][(sl ^ key) * 4] =
          *(const float4*)&ekp[(long long)(b * KDIM + kt * 64 + k) * 64 + sl * 4];
      *(float4*)&vs[k][sl * 4] =
          *(const float4*)&vglob[(long long)(b * KDIM + kt * 64 + k) * 64 + sl * 4];
    }
    __syncthreads();

    // ---- score pipeline (round-3 proven structure) ----
    float acc0 = 0.0f, acc1 = 0.0f, acc2 = 0.0f, acc3 = 0.0f;
    float4 qA, kA0, kA1, kA2, kA3;
    float4 qB, kB0, kB1, kB2, kB3;

#define LOAD_STAGE(QF, K0, K1, K2, K3, H)                  \
  QF = *(const float4*)&qs[tq][(H) * 4];                   \
  K0 = *(const float4*)&ks[kbs + 0][((H) ^ key0) * 4];     \
  K1 = *(const float4*)&ks[kbs + 1][((H) ^ key1) * 4];     \
  K2 = *(const float4*)&ks[kbs + 2][((H) ^ key2) * 4];     \
  K3 = *(const float4*)&ks[kbs + 3][((H) ^ key3) * 4];

#define COMP_STAGE(QF, K0, K1, K2, K3, H)                  \
  {                                                        \
    const float w0 = wv[(H) * 4 + 0];                      \
    const float w1 = wv[(H) * 4 + 1];                      \
    const float w2 = wv[(H) * 4 + 2];                      \
    const float w3 = wv[(H) * 4 + 3];                      \
    acc0 = fmaf(w0, sigp(QF.x, K0.x), acc0);               \
    acc1 = fmaf(w0, sigp(QF.x, K1.x), acc1);               \
    acc2 = fmaf(w0, sigp(QF.x, K2.x), acc2);               \
    acc3 = fmaf(w0, sigp(QF.x, K3.x), acc3);               \
    acc0 = fmaf(w1, sigp(QF.y, K0.y), acc0);               \
    acc1 = fmaf(w1, sigp(QF.y, K1.y), acc1);               \
    acc2 = fmaf(w1, sigp(QF.y, K2.y), acc2);               \
    acc3 = fmaf(w1, sigp(QF.y, K3.y), acc3);               \
    acc0 = fmaf(w2, sigp(QF.z, K0.z), acc0);               \
    acc1 = fmaf(w2, sigp(QF.z, K1.z), acc1);               \
    acc2 = fmaf(w2, sigp(QF.z, K2.z), acc2);               \
    acc3 = fmaf(w2, sigp(QF.z, K3.z), acc3);               \
    acc0 = fmaf(w3, sigp(QF.w, K0.w), acc0);               \
    acc1 = fmaf(w3, sigp(QF.w, K1.w), acc1);               \
    acc2 = fmaf(w3, sigp(QF.w, K2.w), acc2);               \
    acc3 = fmaf(w3, sigp(QF.w, K3.w), acc3);               \
  }

    LOAD_STAGE(qA, kA0, kA1, kA2, kA3, 0)
#pragma unroll
    for (int h = 0; h < 16; h += 2) {
      LOAD_STAGE(qB, kB0, kB1, kB2, kB3, h + 1)
      COMP_STAGE(qA, kA0, kA1, kA2, kA3, h)
      if (h + 2 < 16) LOAD_STAGE(qA, kA0, kA1, kA2, kA3, h + 2)
      COMP_STAGE(qB, kB0, kB1, kB2, kB3, h + 1)
    }
#undef LOAD_STAGE
#undef COMP_STAGE

    const int kbase = kt * 64 + kbs;
    float s0 = fmaf(-2.0f, acc0, sumw);
    float s1 = fmaf(-2.0f, acc1, sumw);
    float s2 = fmaf(-2.0f, acc2, sumw);
    float s3 = fmaf(-2.0f, acc3, sumw);
    s0 = (kbase + 0 < vlen) ? s0 : -3.0e38f;
    s1 = (kbase + 1 < vlen) ? s1 : -3.0e38f;
    s2 = (kbase + 2 < vlen) ? s2 : -3.0e38f;
    s3 = (kbase + 3 < vlen) ? s3 : -3.0e38f;

    // row max over the 16 kg lanes (lanes of a row are contiguous in-wave)
    float tm = fmaxf(fmaxf(s0, s1), fmaxf(s2, s3));
#pragma unroll
    for (int s = 1; s < 16; s <<= 1) tm = fmaxf(tm, __shfl_xor(tm, s, 64));
    const float mn = fmaxf(m, tm);
    const float scale = __builtin_amdgcn_exp2f((m - mn) * kLog2e);
    const float p0 = __builtin_amdgcn_exp2f((s0 - mn) * kLog2e);
    const float p1 = __builtin_amdgcn_exp2f((s1 - mn) * kLog2e);
    const float p2 = __builtin_amdgcn_exp2f((s2 - mn) * kLog2e);
    const float p3 = __builtin_amdgcn_exp2f((s3 - mn) * kLog2e);
    float tsum = (p0 + p1) + (p2 + p3);
#pragma unroll
    for (int s = 1; s < 16; s <<= 1) tsum += __shfl_xor(tsum, s, 64);
    l = fmaf(l, scale, tsum);
    m = mn;
    o4.x *= scale; o4.y *= scale; o4.z *= scale; o4.w *= scale;
    *(float4*)&ps[tq][kbs] = make_float4(p0, p1, p2, p3);
    __syncthreads();

    // ---- PV: o4 += sum_k ps[tq][k] * vs[k][dsl..dsl+3] ----
#pragma unroll 4
    for (int k4 = 0; k4 < 16; ++k4) {
      const float4 p4 = *(const float4*)&ps[tq][k4 * 4];
      const float pw[4] = {p4.x, p4.y, p4.z, p4.w};
#pragma unroll
      for (int e = 0; e < 4; ++e) {
        const float4 vx = *(const float4*)&vs[k4 * 4 + e][kbs];
        o4.x = fmaf(pw[e], vx.x, o4.x);
        o4.y = fmaf(pw[e], vx.y, o4.y);
        o4.z = fmaf(pw[e], vx.z, o4.z);
        o4.w = fmaf(pw[e], vx.w, o4.w);
      }
    }
  }

  // ---- write chunk partials (slot = g) ----
  *(float4*)&part_o[((long long)g * 32 + tq) * 64 + kbs] = o4;
  if (kg == 0) part_ml[g * 32 + tq] = make_float2(m, l);
}

// ---------------------------------------------------------------------------
// K3: combine <=MAXCH chunk partials per q-row. 256 thr = 4 rows x 64 lanes.
// out[row][d] = sum_c w_c*o_c[d] / sum_c w_c*l_c, w_c = e^{m_c - M}.
// ---------------------------------------------------------------------------
__global__ __launch_bounds__(256) void combine_kernel(
    const float* __restrict__ part_o, const float2* __restrict__ part_ml,
    const int* __restrict__ vlens, float* __restrict__ out) {
  int pre[8];
  int nchv[8];
  int run = 0;
#pragma unroll
  for (int bb = 0; bb < 8; ++bb) {
    int nt = (vlens[bb] + 63) >> 6;
    nt = nt < 16 ? nt : 16;
    nchv[bb] = (nt + KTPC - 1) / KTPC;
    pre[bb] = run;
    run += nchv[bb] << 5;
  }
  const int t = threadIdx.x;
  const int row = blockIdx.x * 4 + (t >> 6);
  const int lane = t & 63;
  const int b = row >> 10;
  const int qrow = row & (QDIM - 1);
  const int qt = qrow >> 5;
  const int tq = qrow & 31;
  const int nch = nchv[b];
  const int slot0 = pre[b] + qt;  // slot for chunk c = slot0 + c*32

  float M = -3.0e38f;
  float mv[MAXCH], lv[MAXCH];
#pragma unroll
  for (int c = 0; c < MAXCH; ++c) {
    if (c < nch) {
      const float2 ml = part_ml[(slot0 + c * 32) * 32 + tq];
      mv[c] = ml.x;
      lv[c] = ml.y;
      M = fmaxf(M, ml.x);
    }
  }
  float L = 0.0f, acc = 0.0f;
#pragma unroll
  for (int c = 0; c < MAXCH; ++c) {
    if (c < nch) {
      const float w = __builtin_amdgcn_exp2f((mv[c] - M) * kLog2e);
      L = fmaf(lv[c], w, L);
      const float ov =
          part_o[((long long)(slot0 + c * 32) * 32 + tq) * 64 + lane];
      acc = fmaf(ov, w, acc);
    }
  }
  out[(long long)row * 64 + lane] = acc * __builtin_amdgcn_rcpf(L);
}

// ---------------------------------------------------------------------------
extern "C" void kernel_launch(void* const* d_in, const int* in_sizes, int n_in,
                              void* d_out, int out_size, void* d_ws, size_t ws_size,
                              hipStream_t stream) {
  const float* queries = (const float*)d_in[0];
  const float* keys    = (const float*)d_in[1];
  const float* values  = (const float*)d_in[2];
  const int*   vlens   = (const int*)d_in[3];
  const float* Wq      = (const float*)d_in[4];
  const float* Wk      = (const float*)d_in[5];
  const float* wv      = (const float*)d_in[6];
  float* out = (float*)d_out;

  float*  eq      = (float*)d_ws;                        // B*Q*H = 2 MB
  float*  ek      = eq + (size_t)BDIM * QDIM * HDIM;     // B*K*H = 2 MB
  float*  part_o  = ek + (size_t)BDIM * KDIM * HDIM;     // 1024*32*64 = 8 MB
  float2* part_ml = (float2*)(part_o + (size_t)1024 * 32 * 64);  // 256 KB

  proj_both<<<dim3(256), 256, 0, stream>>>(queries, keys, Wq, Wk, eq, ek);
  // max worklist = 8 b * 4 chunks * 32 q-tiles = 1024; invalid tail exits.
  fused_kernel<<<dim3(1024), 512, 0, stream>>>(eq, ek, values, wv, vlens,
                                               part_o, part_ml);
  combine_kernel<<<dim3(BDIM * QDIM / 4), 256, 0, stream>>>(part_o, part_ml,
                                                            vlens, out);
}

// Round 7
// 83.292 us; speedup vs baseline: 1.3740x; 1.3740x over previous
//
#include <hip/hip_runtime.h>

// Problem sizes (fixed by the reference)
#define BDIM 8
#define QDIM 1024
#define KDIM 1024
#define HDIM 64   // = DQ = DK = DV

constexpr float kLog2e = 1.4426950408889634f;
constexpr float kC2 = 2.0f * kLog2e;

// ---------------------------------------------------------------------------
// K1: both projections; emits Eq/Ek = min(exp2(kC2 * (X@W)), 2^15).
// Clamp makes the quad-rational denominators overflow-proof:
// u = 1+Eq*Ek <= 2^30+1, d01*d23 <= 2^121 < inf. tanh error from clamp <2^-25.
// ---------------------------------------------------------------------------
__global__ __launch_bounds__(256) void proj_both(
    const float* __restrict__ queries, const float* __restrict__ keys,
    const float* __restrict__ Wq, const float* __restrict__ Wk,
    float* __restrict__ eq, float* __restrict__ ek) {
  const int bid = blockIdx.x;
  const bool isK = bid >= 128;
  const float* X = isK ? keys : queries;
  const float* W = isK ? Wk : Wq;
  float* Y = isK ? ek : eq;
  const long long base = (long long)(bid & 127) * 64 * 64;

  __shared__ __align__(16) float xs[64][68];
  __shared__ __align__(16) float ws[64][64];
  const int t = threadIdx.x;
  {
    const int r = t >> 4, sl = t & 15;
#pragma unroll
    for (int i = 0; i < 4; ++i) {
      *(float4*)&xs[r + i * 16][sl * 4] =
          *(const float4*)&X[base + (long long)(r + i * 16) * 64 + sl * 4];
      *(float4*)&ws[r + i * 16][sl * 4] =
          *(const float4*)&W[(r + i * 16) * 64 + sl * 4];
    }
  }
  __syncthreads();

  const int r = t >> 2;
  const int c0 = (t & 3) * 16;
  float acc[16];
#pragma unroll
  for (int j = 0; j < 16; ++j) acc[j] = 0.0f;

#pragma unroll 8
  for (int d = 0; d < 64; ++d) {
    const float xv = xs[r][d];
#pragma unroll
    for (int j4 = 0; j4 < 4; ++j4) {
      float4 w4 = *(float4*)&ws[d][c0 + j4 * 4];
      acc[j4 * 4 + 0] = fmaf(xv, w4.x, acc[j4 * 4 + 0]);
      acc[j4 * 4 + 1] = fmaf(xv, w4.y, acc[j4 * 4 + 1]);
      acc[j4 * 4 + 2] = fmaf(xv, w4.z, acc[j4 * 4 + 2]);
      acc[j4 * 4 + 3] = fmaf(xv, w4.w, acc[j4 * 4 + 3]);
    }
  }
#pragma unroll
  for (int j4 = 0; j4 < 4; ++j4) {
    float4 o = make_float4(
        fminf(__builtin_amdgcn_exp2f(acc[j4 * 4 + 0] * kC2), 32768.0f),
        fminf(__builtin_amdgcn_exp2f(acc[j4 * 4 + 1] * kC2), 32768.0f),
        fminf(__builtin_amdgcn_exp2f(acc[j4 * 4 + 2] * kC2), 32768.0f),
        fminf(__builtin_amdgcn_exp2f(acc[j4 * 4 + 3] * kC2), 32768.0f));
    *(float4*)&Y[base + (long long)r * 64 + c0 + j4 * 4] = o;
  }
}

// ---------------------------------------------------------------------------
// K2: scores[b,q,k] = sumw - 2*sum_h wv[h]/(1+Eq*Ek), output fp16.
// Round-3/5 proven structure (32q x 64k tile, 512 thr, 1q x 4k per thread,
// compacted worklist, reg double-buffered h-pipeline). Math: 4 h-terms share
// one rcp via the quad rational  sum wi/ui = (n01*d23+n23*d01)/(d01*d23),
// ui = fma(Eq,Ek,1): 15 VALU ops / 4 elems = 8.5 cyc/elem (was 12).
// ---------------------------------------------------------------------------
__global__ __launch_bounds__(512, 4) void scores_kernel(
    const float* __restrict__ eqp, const float* __restrict__ ekp,
    const float* __restrict__ wv, const int* __restrict__ vlens,
    _Float16* __restrict__ scores) {
  // ---- uniform worklist mapping (scalar) ----
  int pre[9];
  pre[0] = 0;
#pragma unroll
  for (int bb = 0; bb < 8; ++bb) {
    int nt = (vlens[bb] + 63) >> 6;
    nt = nt < 16 ? nt : 16;
    pre[bb + 1] = pre[bb] + (nt << 5);  // nt k-tiles x 32 q-tiles
  }
  const int g = blockIdx.x;
  if (g >= pre[8]) return;
  int b = 0;
#pragma unroll
  for (int i = 0; i < 7; ++i) b += (g >= pre[i + 1]);
  const int local = g - pre[b];
  const int q0 = (local & 31) * 32;  // q-tile fastest
  const int k0 = (local >> 5) * 64;

  __shared__ __align__(16) float qs[32][68];
  __shared__ __align__(16) float ks[64][64];
  const int t = threadIdx.x;

  float sumw = 0.0f;
#pragma unroll
  for (int h = 0; h < 64; ++h) sumw += wv[h];  // uniform -> scalar loads

  {
    const int r = t >> 4, sl = t & 15;
    *(float4*)&qs[r][sl * 4] =
        *(const float4*)&eqp[(long long)(b * QDIM + q0 + r) * 64 + sl * 4];
  }
#pragma unroll
  for (int i = 0; i < 2; ++i) {
    const int f = i * 512 + t;
    const int k = f >> 4, sl = f & 15;
    const int key = (k ^ (k >> 2)) & 15;
    *(float4*)&ks[k][(sl ^ key) * 4] =
        *(const float4*)&ekp[(long long)(b * KDIM + k0 + k) * 64 + sl * 4];
  }
  __syncthreads();

  const int tq = t >> 4;            // 0..31: q row
  const int kg = t & 15;            // k group
  const int kbs = kg << 2;          // k base = 4*kg
  const int key0 = ((kbs + 0) ^ kg) & 15;
  const int key1 = ((kbs + 1) ^ kg) & 15;
  const int key2 = ((kbs + 2) ^ kg) & 15;
  const int key3 = ((kbs + 3) ^ kg) & 15;

  float acc0 = 0.0f, acc1 = 0.0f, acc2 = 0.0f, acc3 = 0.0f;

  float4 qA, kA0, kA1, kA2, kA3;
  float4 qB, kB0, kB1, kB2, kB3;

#define LOAD_STAGE(QF, K0, K1, K2, K3, H)                  \
  QF = *(const float4*)&qs[tq][(H) * 4];                   \
  K0 = *(const float4*)&ks[kbs + 0][((H) ^ key0) * 4];     \
  K1 = *(const float4*)&ks[kbs + 1][((H) ^ key1) * 4];     \
  K2 = *(const float4*)&ks[kbs + 2][((H) ^ key2) * 4];     \
  K3 = *(const float4*)&ks[kbs + 3][((H) ^ key3) * 4];

// quad rational: acc += (n01*d23 + n23*d01) * rcp(d01*d23)
#define QUAD(ACC, QF, KF, W0, W1, W2, W3)                  \
  {                                                        \
    const float u0 = fmaf(QF.x, KF.x, 1.0f);               \
    const float u1 = fmaf(QF.y, KF.y, 1.0f);               \
    const float u2 = fmaf(QF.z, KF.z, 1.0f);               \
    const float u3 = fmaf(QF.w, KF.w, 1.0f);               \
    const float d01 = u0 * u1;                             \
    const float d23 = u2 * u3;                             \
    const float n01 = fmaf(W1, u0, W0 * u1);               \
    const float n23 = fmaf(W3, u2, W2 * u3);               \
    const float num = fmaf(n23, d01, n01 * d23);           \
    ACC = fmaf(num, __builtin_amdgcn_rcpf(d01 * d23), ACC);\
  }

#define COMP_STAGE(QF, K0, K1, K2, K3, H)                  \
  {                                                        \
    const float w0 = wv[(H) * 4 + 0];                      \
    const float w1 = wv[(H) * 4 + 1];                      \
    const float w2 = wv[(H) * 4 + 2];                      \
    const float w3 = wv[(H) * 4 + 3];                      \
    QUAD(acc0, QF, K0, w0, w1, w2, w3)                     \
    QUAD(acc1, QF, K1, w0, w1, w2, w3)                     \
    QUAD(acc2, QF, K2, w0, w1, w2, w3)                     \
    QUAD(acc3, QF, K3, w0, w1, w2, w3)                     \
  }

  LOAD_STAGE(qA, kA0, kA1, kA2, kA3, 0)
#pragma unroll
  for (int h = 0; h < 16; h += 2) {
    LOAD_STAGE(qB, kB0, kB1, kB2, kB3, h + 1)
    COMP_STAGE(qA, kA0, kA1, kA2, kA3, h)
    if (h + 2 < 16) LOAD_STAGE(qA, kA0, kA1, kA2, kA3, h + 2)
    COMP_STAGE(qB, kB0, kB1, kB2, kB3, h + 1)
  }
#undef LOAD_STAGE
#undef COMP_STAGE
#undef QUAD

  // pack 4 fp32 scores -> 4 fp16 (8B store)
  union { _Float16 h[4]; uint2 v; } pk;
  pk.h[0] = (_Float16)fmaf(-2.0f, acc0, sumw);
  pk.h[1] = (_Float16)fmaf(-2.0f, acc1, sumw);
  pk.h[2] = (_Float16)fmaf(-2.0f, acc2, sumw);
  pk.h[3] = (_Float16)fmaf(-2.0f, acc3, sumw);
  *(uint2*)&scores[(long long)(b * QDIM + q0 + tq) * KDIM + k0 + kbs] = pk.v;
}

// ---------------------------------------------------------------------------
// K3: fused masked-softmax + PV over fp16 scores. Block = 8 q-rows x 32
// lanes-of-d (256 thr), 1024 blocks -> 4 blocks/CU (16 waves/CU). k tiled by
// 128: per tile load V->LDS, read 4 fp16 scores/thread, online (m,l), ps->LDS,
// PV accumulate (thread owns 2 d-floats).
// ---------------------------------------------------------------------------
__global__ __launch_bounds__(256) void softpv_kernel(
    const _Float16* __restrict__ scores, const float* __restrict__ V,
    const int* __restrict__ vlens, float* __restrict__ out) {
  const int b = blockIdx.y;
  const int q0 = blockIdx.x * 8;
  const int vlen = vlens[b];
  const int ntiles = (vlen + 127) >> 7;

  __shared__ __align__(16) float vs[128][64];   // 32 KB
  __shared__ __align__(16) float ps[8][132];
  const int t = threadIdx.x;
  const int r = t >> 5;            // q row 0..7
  const int lane = t & 31;
  const int d2 = lane * 2;         // this thread's 2 d columns
  const _Float16* srow = scores + (long long)(b * QDIM + q0 + r) * KDIM;

  float2 o2 = make_float2(0.0f, 0.0f);
  float m = -3.0e38f, l = 0.0f;

  for (int kt = 0; kt < ntiles; ++kt) {
    // V tile -> LDS (128 rows x 64 d = 2048 float4, 8 per thread)
#pragma unroll
    for (int i = 0; i < 8; ++i) {
      const int f = i * 256 + t;
      const int k = f >> 4, sl = f & 15;
      *(float4*)&vs[k][sl * 4] =
          *(const float4*)&V[(long long)(b * KDIM + kt * 128 + k) * 64 + sl * 4];
    }
    // this thread's 4 fp16 scores + mask
    const int kbase = kt * 128 + lane * 4;
    union { uint2 v; _Float16 h[4]; } rd;
    rd.v = *(const uint2*)&srow[kbase];
    float s0 = (kbase + 0 < vlen) ? (float)rd.h[0] : -3.0e38f;
    float s1 = (kbase + 1 < vlen) ? (float)rd.h[1] : -3.0e38f;
    float s2 = (kbase + 2 < vlen) ? (float)rd.h[2] : -3.0e38f;
    float s3 = (kbase + 3 < vlen) ? (float)rd.h[3] : -3.0e38f;
    float tm = fmaxf(fmaxf(s0, s1), fmaxf(s2, s3));
#pragma unroll
    for (int s = 1; s < 32; s <<= 1) tm = fmaxf(tm, __shfl_xor(tm, s, 64));
    const float mn = fmaxf(m, tm);
    const float scale = __builtin_amdgcn_exp2f((m - mn) * kLog2e);
    const float p0 = __builtin_amdgcn_exp2f((s0 - mn) * kLog2e);
    const float p1 = __builtin_amdgcn_exp2f((s1 - mn) * kLog2e);
    const float p2 = __builtin_amdgcn_exp2f((s2 - mn) * kLog2e);
    const float p3 = __builtin_amdgcn_exp2f((s3 - mn) * kLog2e);
    float tsum = (p0 + p1) + (p2 + p3);
#pragma unroll
    for (int s = 1; s < 32; s <<= 1) tsum += __shfl_xor(tsum, s, 64);
    l = fmaf(l, scale, tsum);
    m = mn;
    o2.x *= scale; o2.y *= scale;
    *(float4*)&ps[r][lane * 4] = make_float4(p0, p1, p2, p3);
    __syncthreads();

    // PV: o2 += sum_k ps[r][k] * vs[k][d2..d2+1]
#pragma unroll 8
    for (int k4 = 0; k4 < 32; ++k4) {
      const float4 p4 = *(const float4*)&ps[r][k4 * 4];
      const float pw[4] = {p4.x, p4.y, p4.z, p4.w};
#pragma unroll
      for (int e = 0; e < 4; ++e) {
        const float2 vv = *(const float2*)&vs[k4 * 4 + e][d2];
        o2.x = fmaf(pw[e], vv.x, o2.x);
        o2.y = fmaf(pw[e], vv.y, o2.y);
      }
    }
    __syncthreads();
  }

  const float inv = __builtin_amdgcn_rcpf(l);
  *(float2*)&out[(long long)(b * QDIM + q0 + r) * 64 + d2] =
      make_float2(o2.x * inv, o2.y * inv);
}

// ---------------------------------------------------------------------------
extern "C" void kernel_launch(void* const* d_in, const int* in_sizes, int n_in,
                              void* d_out, int out_size, void* d_ws, size_t ws_size,
                              hipStream_t stream) {
  const float* queries = (const float*)d_in[0];
  const float* keys    = (const float*)d_in[1];
  const float* values  = (const float*)d_in[2];
  const int*   vlens   = (const int*)d_in[3];
  const float* Wq      = (const float*)d_in[4];
  const float* Wk      = (const float*)d_in[5];
  const float* wv      = (const float*)d_in[6];
  float* out = (float*)d_out;

  float*     eq     = (float*)d_ws;                     // B*Q*H = 2 MB
  float*     ek     = eq + (size_t)BDIM * QDIM * HDIM;  // B*K*H = 2 MB
  _Float16*  scores = (_Float16*)(ek + (size_t)BDIM * KDIM * HDIM);  // 16 MB

  proj_both<<<dim3(256), 256, 0, stream>>>(queries, keys, Wq, Wk, eq, ek);
  // max tiles = 8 b * 32 q-tiles * 16 k-tiles = 4096; invalid tail exits fast.
  scores_kernel<<<dim3(4096), 512, 0, stream>>>(eq, ek, wv, vlens, scores);
  softpv_kernel<<<dim3(QDIM / 8, BDIM), 256, 0, stream>>>(scores, values,
                                                          vlens, out);
}